// Round 7
// baseline (28.750 us; speedup 1.0000x reference)
//
#include <hip/hip_runtime.h>

// Gaussian-splat heatmap as a per-image MFMA GEMM — single pass, accs in registers.
//   heat[y][x] = sum_p Rmat[y][p] * CmatT[x][p]   (M=200, N=200, K=64 points)
// Rmat[y][p]  = k1n[y-ys_p] if 0<=y-ys_p<ky_p else 0   (top-left-slice quirk)
// CmatT[x][p] = k1n[x-xs_p] if 0<=x-xs_p<kx_p else 0
// bf16 LDS [224][64] per matrix (pad rows 200-223 are zero since ys,xs<=164,
// ky,kx<=36). Row = 128 B, XOR-swizzled byte ^= ((row&7)<<4) (G4/T2).
// mfma_f32_32x32x16_bf16, 7x7 tiles of 32, K=64 -> 4 MFMA/tile.
//   A-frag: lane l -> row l&31, k = 8*(l>>5)+j  (one b128 per MFMA)
//   C/D:    col = lane&31, row = (reg&3)+8*(reg>>2)+4*(lane>>5)  [m74/m101]
// 448 threads = 7 waves; wave w owns tile-row w and keeps all 7 tiles'
// accumulators in registers (7 x f32x16 = 112 VGPR, fully unrolled -> no
// scratch). Single MFMA pass; block max reduced from the registers; scale and
// store directly from registers. Halves the MFMA/LDS work of the 2-pass r6
// version and lets stores begin right after the max reduce.

#define NT 64
#define BLK 448
#define TDIM 224
#define NTL 7            // 7 tiles of 32 per dim

typedef short bf16x8 __attribute__((ext_vector_type(8)));
typedef float f32x16 __attribute__((ext_vector_type(16)));

// f32 -> bf16 round-to-nearest-even
static __device__ inline unsigned short f2bf(float f) {
    unsigned int u = __float_as_uint(f);
    u = (u + 0x7FFFu + ((u >> 16) & 1u)) >> 16;
    return (unsigned short)u;
}

struct __align__(16) SMem {
    unsigned short Rm[TDIM][64];   // 28,672 B, swizzled
    unsigned short Cm[TDIM][64];   // 28,672 B, swizzled
    unsigned short k1b[40];        // bf16 normalized 1-D gaussian
    float wmax[NTL];
};

__global__ __launch_bounds__(BLK) void heatmap_kernel(const float* __restrict__ x_t,
                                                      float* __restrict__ out) {
    __shared__ SMem s;
    const int tid  = threadIdx.x;
    const int lane = tid & 63;
    const int wv   = tid >> 6;      // 0..6
    const int b    = blockIdx.x;

    // --- normalized 1-D gaussian table, bf16 ---
    if (tid < 37) {
        float sum = 0.0f, mine = 0.0f;
        #pragma unroll
        for (int i = 0; i < 37; ++i) {
            float r = (float)(i - 18);
            float v = expf(-(r * r) * (1.0f / 18.0f));   // sigma=3 -> 2*sigma^2=18
            sum += v;
            if (i == tid) mine = v;
        }
        s.k1b[tid] = f2bf(mine / sum);
    }
    __syncthreads();

    // --- build Rm (rows=y) and Cm (rows=x); thread = (point-pair q, row-group r0) ---
    {
        const int q  = tid & 31;    // points 2q, 2q+1
        const int r0 = tid >> 5;    // 0..13; rows r0 + 14*i, i=0..15 cover 0..223
        float4 pxy = *(const float4*)(x_t + (size_t)b * NT * 2 + 4 * q);
        // point 2q  (replicates reference exactly)
        bool v0 = (pxy.x == pxy.x) && (pxy.y == pxy.y);
        int xp0 = (int)(pxy.x * 2.0f), yp0 = 200 - (int)(pxy.y * 2.0f);
        int xs0 = min(max(xp0 - 18, 0), 164), ys0 = min(max(yp0 - 18, 0), 164);
        int kx0 = v0 ? (min(max(xp0 + 18, 0), 200) - xs0) : 0;
        int ky0 = v0 ? (min(max(yp0 + 18, 0), 200) - ys0) : 0;
        // point 2q+1
        bool v1 = (pxy.z == pxy.z) && (pxy.w == pxy.w);
        int xp1 = (int)(pxy.z * 2.0f), yp1 = 200 - (int)(pxy.w * 2.0f);
        int xs1 = min(max(xp1 - 18, 0), 164), ys1 = min(max(yp1 - 18, 0), 164);
        int kx1 = v1 ? (min(max(xp1 + 18, 0), 200) - xs1) : 0;
        int ky1 = v1 ? (min(max(yp1 + 18, 0), 200) - ys1) : 0;

        #pragma unroll
        for (int i = 0; i < 16; ++i) {
            int row = r0 + 14 * i;
            int sw  = (4 * q) ^ ((row & 7) << 4);
            int d0 = row - ys0, d1 = row - ys1;
            unsigned a0 = ((unsigned)d0 < (unsigned)ky0) ? s.k1b[d0] : 0u;
            unsigned a1 = ((unsigned)d1 < (unsigned)ky1) ? s.k1b[d1] : 0u;
            *(unsigned*)((char*)s.Rm + row * 128 + sw) = a0 | (a1 << 16);
            int e0 = row - xs0, e1 = row - xs1;
            unsigned c0 = ((unsigned)e0 < (unsigned)kx0) ? s.k1b[e0] : 0u;
            unsigned c1 = ((unsigned)e1 < (unsigned)kx1) ? s.k1b[e1] : 0u;
            *(unsigned*)((char*)s.Cm + row * 128 + sw) = c0 | (c1 << 16);
        }
    }
    __syncthreads();

    const int swl = (lane & 7) << 4;    // swizzle term (rows = t*32+(lane&31))

    // --- A fragments for this wave's tile-row ---
    bf16x8 A[4];
    {
        const char* ab = (const char*)s.Rm + (wv * 32 + (lane & 31)) * 128;
        #pragma unroll
        for (int m = 0; m < 4; ++m)
            A[m] = *(const bf16x8*)(ab + ((16 * (2 * m + (lane >> 5))) ^ swl));
    }

    // --- single MFMA pass; keep all 7 tiles' accumulators in registers ---
    f32x16 acc[NTL];
    #pragma unroll
    for (int tx = 0; tx < NTL; ++tx) {
        #pragma unroll
        for (int r = 0; r < 16; ++r) acc[tx][r] = 0.0f;
    }
    #pragma unroll
    for (int tx = 0; tx < NTL; ++tx) {
        const char* bb = (const char*)s.Cm + (tx * 32 + (lane & 31)) * 128;
        #pragma unroll
        for (int m = 0; m < 4; ++m) {
            bf16x8 B = *(const bf16x8*)(bb + ((16 * (2 * m + (lane >> 5))) ^ swl));
            acc[tx] = __builtin_amdgcn_mfma_f32_32x32x16_bf16(A[m], B, acc[tx], 0, 0, 0);
        }
    }

    // --- block max directly from registers ---
    float gmax = 0.0f;
    #pragma unroll
    for (int tx = 0; tx < NTL; ++tx) {
        #pragma unroll
        for (int r = 0; r < 16; ++r) gmax = fmaxf(gmax, acc[tx][r]);
    }
    #pragma unroll
    for (int off = 32; off > 0; off >>= 1) gmax = fmaxf(gmax, __shfl_xor(gmax, off));
    if (lane == 0) s.wmax[wv] = gmax;
    __syncthreads();
    float mm = s.wmax[0];
    #pragma unroll
    for (int w = 1; w < NTL; ++w) mm = fmaxf(mm, s.wmax[w]);
    const float scale = 1.0f / (mm + 1e-10f);

    // --- scale + store from registers ---
    float* ob = out + (size_t)b * (200 * 200);
    const int colbase = lane & 31;
    const int rowoff  = wv * 32 + 4 * (lane >> 5);
    #pragma unroll
    for (int tx = 0; tx < NTL; ++tx) {
        const int gcol = tx * 32 + colbase;
        #pragma unroll
        for (int r = 0; r < 16; ++r) {
            int grow = rowoff + (r & 3) + 8 * (r >> 2);
            if (grow < 200 && gcol < 200)
                ob[grow * 200 + gcol] = acc[tx][r] * scale;
        }
    }
}

extern "C" void kernel_launch(void* const* d_in, const int* in_sizes, int n_in,
                              void* d_out, int out_size, void* d_ws, size_t ws_size,
                              hipStream_t stream) {
    const float* x_t = (const float*)d_in[0];
    float* out = (float*)d_out;
    const int B = in_sizes[0] / (NT * 2);   // 512
    heatmap_kernel<<<B, BLK, 0, stream>>>(x_t, out);
}